// Round 3
// baseline (263.628 us; speedup 1.0000x reference)
//
#include <hip/hip_runtime.h>
#include <math.h>

#define BB 8
#define TT 1024
#define CC 768
#define NH 12
#define HD 64
#define LOG2E 1.44269504088896f

typedef __attribute__((ext_vector_type(8))) _Float16 hv8;   // 8 fp16 (4 VGPRs)
typedef __attribute__((ext_vector_type(8))) short  short8;  // raw 16B
typedef __attribute__((ext_vector_type(4))) float  f32x4;

static __device__ __forceinline__ float fast_exp2(float x) {
#if __has_builtin(__builtin_amdgcn_exp2f)
    return __builtin_amdgcn_exp2f(x);
#else
    return exp2f(x);
#endif
}

// ---------------------------------------------------------------------------
// All 4 weight transposes in one launch: WT[n][k] = W[k][n] * scale (fp16).
// Score scale 0.125 AND log2(e) folded into Wk -> scores arrive in exp2
// domain (attn uses v_exp_f32 directly, no per-element mul).
// ---------------------------------------------------------------------------
__global__ __launch_bounds__(256) void transpose_w4(
    const float* __restrict__ Wq, const float* __restrict__ Wk,
    const float* __restrict__ Wv, const float* __restrict__ Wo,
    _Float16* __restrict__ WqT, _Float16* __restrict__ WkT,
    _Float16* __restrict__ WvT, _Float16* __restrict__ WoT)
{
    const int z = blockIdx.z;
    const float* W = (z == 0) ? Wq : (z == 1) ? Wk : (z == 2) ? Wv : Wo;
    _Float16*   WT = (z == 0) ? WqT : (z == 1) ? WkT : (z == 2) ? WvT : WoT;
    const float scale = (z == 1) ? 0.125f * LOG2E : 1.0f;

    __shared__ float tile[64][65];
    const int tx = threadIdx.x & 15, ty = threadIdx.x >> 4;
    const int n0 = blockIdx.x * 64, k0 = blockIdx.y * 64;

    #pragma unroll
    for (int ii = 0; ii < 4; ++ii) {
        int k = ty + ii * 16;
        float4 v = *(const float4*)(W + (size_t)(k0 + k) * CC + n0 + tx * 4);
        tile[k][tx*4+0] = v.x; tile[k][tx*4+1] = v.y;
        tile[k][tx*4+2] = v.z; tile[k][tx*4+3] = v.w;
    }
    __syncthreads();
    #pragma unroll
    for (int ii = 0; ii < 4; ++ii) {
        int n = ty + ii * 16;
        _Float16* dst = WT + (size_t)(n0 + n) * CC + k0 + tx * 4;
        dst[0] = (_Float16)(tile[tx*4+0][n] * scale);
        dst[1] = (_Float16)(tile[tx*4+1][n] * scale);
        dst[2] = (_Float16)(tile[tx*4+2][n] * scale);
        dst[3] = (_Float16)(tile[tx*4+3][n] * scale);
    }
}

// ---------------------------------------------------------------------------
// Fused QKV GEMM, one launch (grid.z = 0/1/2 -> Q/K/V).
// R3: T14 register prefetch double-buffer -- tile kt held in regs (A raw
// f32, cvt at LDS-write time), loads for kt+1 issued BEFORE compute so HBM
// latency hides under the MFMA cluster.  R2's version drained vmcnt into a
// barrier every kt (warm dispatches: 83us at 5.6% HBM = latency-bound).
// z<2: LDS-bounce vectorized epilogue into [b,h,t,d].
// z==2 (V): stride-137 transpose bounce, t-contiguous stores into [b,h,d,t].
// ---------------------------------------------------------------------------
__global__ __launch_bounds__(256) void gemm_qkv3(
    const float* __restrict__ x, const float* __restrict__ ctx,
    const _Float16* __restrict__ WqT, const _Float16* __restrict__ WkT,
    const _Float16* __restrict__ WvT,
    _Float16* __restrict__ Qh, _Float16* __restrict__ Kh,
    _Float16* __restrict__ Vt)
{
    const int z = blockIdx.z;
    const float* A      = (z == 0) ? x : ctx;
    const _Float16* BT  = (z == 0) ? WqT : (z == 1) ? WkT : WvT;

    __shared__ _Float16 smem[2 * 128 * 72];   // sA | sB ; reused as sT bounce
    _Float16* sA = smem;
    _Float16* sB = smem + 128 * 72;

    const int tid  = threadIdx.x;
    const int wave = tid >> 6, lane = tid & 63;
    const int quad = lane >> 4, l16 = lane & 15;
    const int m0 = blockIdx.y * 128, n0 = blockIdx.x * 128;
    const int mw = (wave & 1) * 64, nw = (wave >> 1) * 64;

    // ---- prefetch registers: tile kt in flight (A raw f32, B f16)
    float4 pA[4][2];
    short8 pB[4];
    auto loadAB = [&](int kt) {
        #pragma unroll
        for (int ii = 0; ii < 4; ++ii) {
            int u = tid + ii * 256;
            int row = u >> 3, c8 = u & 7;
            const float* src = A + (size_t)(m0 + row) * CC + kt + c8*8;
            pA[ii][0] = *(const float4*)(src);
            pA[ii][1] = *(const float4*)(src + 4);
            pB[ii] = *(const short8*)(BT + (size_t)(n0 + row) * CC + kt + c8*8);
        }
    };
    auto writeAB = [&]() {
        #pragma unroll
        for (int ii = 0; ii < 4; ++ii) {
            int u = tid + ii * 256;
            int row = u >> 3, c8 = u & 7;
            float4 v0 = pA[ii][0], v1 = pA[ii][1];
            hv8 hx = { (_Float16)v0.x, (_Float16)v0.y, (_Float16)v0.z, (_Float16)v0.w,
                       (_Float16)v1.x, (_Float16)v1.y, (_Float16)v1.z, (_Float16)v1.w };
            *(hv8*)&sA[row*72 + c8*8] = hx;
            *(short8*)&sB[row*72 + c8*8] = pB[ii];
        }
    };

    f32x4 acc[4][4];
    #pragma unroll
    for (int i = 0; i < 4; ++i)
        #pragma unroll
        for (int j = 0; j < 4; ++j) acc[i][j] = (f32x4){0.f,0.f,0.f,0.f};

    loadAB(0);
    for (int it = 0; it < 12; ++it) {
        writeAB();                       // vmcnt wait happened under prev compute
        __syncthreads();                 // tile it visible
        if (it < 11) loadAB((it + 1) * 64);   // issue next loads early
        #pragma unroll
        for (int kk = 0; kk < 2; ++kk) {
            hv8 af[4], bf[4];
            #pragma unroll
            for (int mi = 0; mi < 4; ++mi)
                af[mi] = *(const hv8*)&sA[(mw + mi*16 + l16)*72 + kk*32 + quad*8];
            #pragma unroll
            for (int nj = 0; nj < 4; ++nj)
                bf[nj] = *(const hv8*)&sB[(nw + nj*16 + l16)*72 + kk*32 + quad*8];
            #pragma unroll
            for (int mi = 0; mi < 4; ++mi)
                #pragma unroll
                for (int nj = 0; nj < 4; ++nj)
                    acc[mi][nj] = __builtin_amdgcn_mfma_f32_16x16x32_f16(
                        af[mi], bf[nj], acc[mi][nj], 0, 0, 0);
        }
        __syncthreads();                 // all waves done reading tile it
    }

    if (z < 2) {
        // row-major bounce -> hv8 stores (128B segments) into [b,h,t,d]
        _Float16* Chead = (z == 0) ? Qh : Kh;
        _Float16* sT = smem;   // [128][137]
        #pragma unroll
        for (int mi = 0; mi < 4; ++mi)
            #pragma unroll
            for (int nj = 0; nj < 4; ++nj)
                #pragma unroll
                for (int r = 0; r < 4; ++r)
                    sT[(mw + mi*16 + quad*4 + r)*137 + nw + nj*16 + l16] =
                        (_Float16)acc[mi][nj][r];
        __syncthreads();
        #pragma unroll
        for (int ii = 0; ii < 8; ++ii) {
            int u = tid + ii * 256;
            int row = u >> 4;           // 0..127
            int ch  = u & 15;           // 16 chunks of 8 halves
            hv8 o;
            #pragma unroll
            for (int j = 0; j < 8; ++j) o[j] = sT[row*137 + ch*8 + j];
            int gm = m0 + row, gn = n0 + ch*8;
            int bI = gm >> 10, tI = gm & 1023;
            int hI = gn >> 6,  dI = gn & 63;
            *(hv8*)(Chead + (((size_t)bI * NH + hI) * TT + tI) * HD + dI) = o;
        }
    } else {
        // V: stride-137 transpose bounce, then t-contiguous stores.
        _Float16* sT = smem;   // [128][137] = 17536 halves <= 18432
        #pragma unroll
        for (int mi = 0; mi < 4; ++mi)
            #pragma unroll
            for (int nj = 0; nj < 4; ++nj)
                #pragma unroll
                for (int r = 0; r < 4; ++r)
                    sT[(mw + mi*16 + quad*4 + r)*137 + nw + nj*16 + l16] =
                        (_Float16)acc[mi][nj][r];
        __syncthreads();
        #pragma unroll
        for (int ii = 0; ii < 8; ++ii) {
            int u = tid + ii * 256;
            int dloc = u >> 4;          // 0..127
            int tch  = u & 15;          // consecutive lanes -> consecutive t
            hv8 o;
            #pragma unroll
            for (int j = 0; j < 8; ++j) o[j] = sT[(tch*8 + j)*137 + dloc];
            int gn = n0 + dloc;
            int hI = gn >> 6, dI = gn & 63;
            int gm = m0 + tch * 8;
            int bI = gm >> 10, tI = gm & 1023;
            *(hv8*)(Vt + (((size_t)bI * NH + hI) * HD + dI) * TT + tI) = o;
        }
    }
}

// ---------------------------------------------------------------------------
// fp16 single-pass output GEMM: out(fp32) = A @ BT^T + bias
// Tile 128x64, grid (12,64) = 768 blocks = exactly 3/CU.
// R3: T14 register prefetch (same pattern as gemm_qkv3).
// ---------------------------------------------------------------------------
__global__ __launch_bounds__(256) void gemm_out_f16(
    const _Float16* __restrict__ A, const _Float16* __restrict__ BT,
    const float* __restrict__ bias, float* __restrict__ out)
{
    __shared__ _Float16 sA[128][72];
    __shared__ _Float16 sB[64][72];

    const int tid  = threadIdx.x;
    const int wave = tid >> 6, lane = tid & 63;
    const int quad = lane >> 4, l16 = lane & 15;
    const int m0 = blockIdx.y * 128, n0 = blockIdx.x * 64;
    const int mw = (wave & 1) * 64, nw = (wave >> 1) * 32;

    short8 pA[4], pB[2];
    auto loadAB = [&](int kt) {
        #pragma unroll
        for (int ii = 0; ii < 4; ++ii) {
            int u = tid + ii * 256;
            int row = u >> 3, c8 = u & 7;
            pA[ii] = *(const short8*)(A + (size_t)(m0 + row) * CC + kt + c8*8);
        }
        #pragma unroll
        for (int ii = 0; ii < 2; ++ii) {
            int u = tid + ii * 256;
            int row = u >> 3, c8 = u & 7;
            pB[ii] = *(const short8*)(BT + (size_t)(n0 + row) * CC + kt + c8*8);
        }
    };
    auto writeAB = [&]() {
        #pragma unroll
        for (int ii = 0; ii < 4; ++ii) {
            int u = tid + ii * 256;
            int row = u >> 3, c8 = u & 7;
            *(short8*)&sA[row][c8*8] = pA[ii];
        }
        #pragma unroll
        for (int ii = 0; ii < 2; ++ii) {
            int u = tid + ii * 256;
            int row = u >> 3, c8 = u & 7;
            *(short8*)&sB[row][c8*8] = pB[ii];
        }
    };

    f32x4 acc[4][2];
    #pragma unroll
    for (int i = 0; i < 4; ++i)
        #pragma unroll
        for (int j = 0; j < 2; ++j) acc[i][j] = (f32x4){0.f,0.f,0.f,0.f};

    loadAB(0);
    for (int it = 0; it < 12; ++it) {
        writeAB();
        __syncthreads();
        if (it < 11) loadAB((it + 1) * 64);
        #pragma unroll
        for (int kk = 0; kk < 2; ++kk) {
            hv8 af[4], bf[2];
            #pragma unroll
            for (int mi = 0; mi < 4; ++mi)
                af[mi] = *(const hv8*)&sA[mw + mi*16 + l16][kk*32 + quad*8];
            #pragma unroll
            for (int nj = 0; nj < 2; ++nj)
                bf[nj] = *(const hv8*)&sB[nw + nj*16 + l16][kk*32 + quad*8];
            #pragma unroll
            for (int mi = 0; mi < 4; ++mi)
                #pragma unroll
                for (int nj = 0; nj < 2; ++nj)
                    acc[mi][nj] = __builtin_amdgcn_mfma_f32_16x16x32_f16(
                        af[mi], bf[nj], acc[mi][nj], 0, 0, 0);
        }
        __syncthreads();
    }

    #pragma unroll
    for (int mi = 0; mi < 4; ++mi)
        #pragma unroll
        for (int nj = 0; nj < 2; ++nj)
            #pragma unroll
            for (int r = 0; r < 4; ++r) {
                int gm = m0 + mw + mi*16 + quad*4 + r;
                int gn = n0 + nw + nj*16 + l16;
                out[(size_t)gm * CC + gn] = acc[mi][nj][r] + bias[gn];
            }
}

// ---------------------------------------------------------------------------
// fp16 MFMA flash attention, BQ=128: 4 waves, each owns 32 q-rows.
// (unchanged from R1 -- MFMA rowsum, exp2 domain, sP XOR swizzle, T14 async
// staging, setprio around PV.)
// ---------------------------------------------------------------------------
#define PW2 (32*72 + 8)   // per-wave sP region stride (halves)

__global__ __launch_bounds__(256) void attn_mfma(
    const _Float16* __restrict__ Q, const _Float16* __restrict__ K,
    const _Float16* __restrict__ Vt, const float* __restrict__ relh,
    const float* __restrict__ relw, _Float16* __restrict__ O)
{
    __shared__ _Float16 sK [64][72];   // loop: K tile | prologue: relh window (35 rows)
    __shared__ _Float16 sVt[64][72];   // loop: Vt tile | prologue: relw rows
    __shared__ _Float16 sP [4*PW2];    // loop: per-wave P (32x64, XOR-swizzled) | prologue: Q + G
    __shared__ _Float16 sH [128][34];  // rh table [qi][hk]

    const int tid  = threadIdx.x;
    const int wave = tid >> 6, lane = tid & 63;
    const int quad = lane >> 4, l16 = lane & 15;

    const int bid = blockIdx.x;
    const int qt  = bid & 7;           // 128-row q tile, 8 per head
    const int bh  = bid >> 3;
    const int h   = bh % NH;
    const int b   = bh / NH;
    const size_t hbase = ((size_t)b * NH + h) * TT * HD;

    // ---- K/V tile prefetch registers (async staging)
    short8 pK[2], pV[2];
    auto loadKV = [&](int kt) {
        #pragma unroll
        for (int ii = 0; ii < 2; ++ii) {
            int u = tid + ii * 256;
            int row = u >> 3, c8 = u & 7;
            pK[ii] = *(const short8*)(K  + hbase + (size_t)(kt*64 + row) * HD + c8*8);
            pV[ii] = *(const short8*)(Vt + hbase + (size_t)row * TT + kt*64 + c8*8);
        }
    };
    auto writeKV = [&]() {
        #pragma unroll
        for (int ii = 0; ii < 2; ++ii) {
            int u = tid + ii * 256;
            int row = u >> 3, c8 = u & 7;
            *(short8*)&sK [row][c8*8] = pK[ii];
            *(short8*)&sVt[row][c8*8] = pV[ii];
        }
    };

    // ---- prologue staging: Q (stride-72 overlay on sP), relh window, relw
    //      relh/relw pre-scaled by log2e (exp2 domain).
    #pragma unroll
    for (int ii = 0; ii < 4; ++ii) {
        int u = tid + ii * 256;        // 0..1023
        int row = u >> 3, c8 = u & 7;
        *(short8*)&sP[row*72 + c8*8] =
            *(const short8*)(Q + hbase + (size_t)(qt*128 + row) * HD + c8*8);
    }
    #pragma unroll
    for (int ii = 0; ii < 2; ++ii) {
        int u = tid + ii * 256;
        if (u < 280) {                 // 35 rows x 8 chunks of relh window
            int row = u >> 3, c8 = u & 7;
            const float* src = relh + (size_t)(4*qt + row) * HD + c8*8;
            float4 v0 = *(const float4*)(src);
            float4 v1 = *(const float4*)(src + 4);
            hv8 s = { (_Float16)(v0.x*LOG2E), (_Float16)(v0.y*LOG2E),
                      (_Float16)(v0.z*LOG2E), (_Float16)(v0.w*LOG2E),
                      (_Float16)(v1.x*LOG2E), (_Float16)(v1.y*LOG2E),
                      (_Float16)(v1.z*LOG2E), (_Float16)(v1.w*LOG2E) };
            *(hv8*)&sK[row][c8*8] = s;
        }
    }
    #pragma unroll
    for (int ii = 0; ii < 2; ++ii) {
        int u = tid + ii * 256;
        int row = u >> 3, c8 = u & 7;
        int sr = row < 63 ? row : 62;
        const float* src = relw + (size_t)sr * HD + c8*8;
        float4 v0 = *(const float4*)(src);
        float4 v1 = *(const float4*)(src + 4);
        hv8 s = { (_Float16)(v0.x*LOG2E), (_Float16)(v0.y*LOG2E),
                  (_Float16)(v0.z*LOG2E), (_Float16)(v0.w*LOG2E),
                  (_Float16)(v1.x*LOG2E), (_Float16)(v1.y*LOG2E),
                  (_Float16)(v1.z*LOG2E), (_Float16)(v1.w*LOG2E) };
        *(hv8*)&sVt[row][c8*8] = s;
    }
    loadKV(0);                         // k-tile 0 in flight during prologue math
    __syncthreads();

    // ---- persistent Q A-fragments (2 groups of 16 rows per wave)
    hv8 aQ0[2], aQ1[2];
    #pragma unroll
    for (int g = 0; g < 2; ++g) {
        int qrow = wave*32 + g*16 + l16;
        aQ0[g] = *(const hv8*)&sP[qrow*72 + quad*8];
        aQ1[g] = *(const hv8*)&sP[qrow*72 + 32 + quad*8];
    }
    __syncthreads();   // all aQ loaded before G-writes clobber the overlay

    // ---- RH via MFMA: sH[qi][hk] = q . relh[hq-hk+31]; hq = qt*4+wave
    #pragma unroll
    for (int g = 0; g < 2; ++g)
        #pragma unroll
        for (int t = 0; t < 2; ++t) {
            int wr = wave + 31 - (t*16 + l16);       // window row, in [wave, wave+31]
            hv8 b0 = *(const hv8*)&sK[wr][quad*8];
            hv8 b1 = *(const hv8*)&sK[wr][32 + quad*8];
            f32x4 c = {0.f,0.f,0.f,0.f};
            c = __builtin_amdgcn_mfma_f32_16x16x32_f16(aQ0[g], b0, c, 0, 0, 0);
            c = __builtin_amdgcn_mfma_f32_16x16x32_f16(aQ1[g], b1, c, 0, 0, 0);
            #pragma unroll
            for (int r = 0; r < 4; ++r)
                sH[wave*32 + g*16 + quad*4 + r][t*16 + l16] = (_Float16)c[r];
        }
    // ---- G = Q @ relw^T into own-wave sP region (XOR-swizzled col blocks)
    #pragma unroll
    for (int g = 0; g < 2; ++g)
        #pragma unroll
        for (int t = 0; t < 4; ++t) {
            hv8 b0 = *(const hv8*)&sVt[t*16 + l16][quad*8];
            hv8 b1 = *(const hv8*)&sVt[t*16 + l16][32 + quad*8];
            f32x4 c = {0.f,0.f,0.f,0.f};
            c = __builtin_amdgcn_mfma_f32_16x16x32_f16(aQ0[g], b0, c, 0, 0, 0);
            c = __builtin_amdgcn_mfma_f32_16x16x32_f16(aQ1[g], b1, c, 0, 0, 0);
            #pragma unroll
            for (int r = 0; r < 4; ++r)
                sP[wave*PW2 + (g*16 + quad*4 + r)*72 + ((t ^ quad) << 4) + l16] =
                    (_Float16)c[r];
        }
    // ---- gather RW bias (own wave region; lgkmcnt orders same-wave LDS)
    float rwReg[2][2][4];
    #pragma unroll
    for (int g = 0; g < 2; ++g)
        #pragma unroll
        for (int j = 0; j < 2; ++j)
            #pragma unroll
            for (int r = 0; r < 4; ++r) {
                int idx = g*16 + quad*4 + r - j*16 - l16 + 31;   // 0..62 logical col
                int pc  = (((idx >> 4) ^ quad) << 4) | (idx & 15);
                rwReg[g][j][r] = (float)sP[wave*PW2 + (g*16 + quad*4 + r)*72 + pc];
            }
    __syncthreads();   // RH/RW reads of sK/sVt complete
    writeKV();         // k-tile 0 -> LDS
    __syncthreads();

    f32x4 o[2][4];
    #pragma unroll
    for (int g = 0; g < 2; ++g)
        #pragma unroll
        for (int n = 0; n < 4; ++n) o[g][n] = (f32x4){0.f,0.f,0.f,0.f};
    f32x4 lacc[2] = { (f32x4){0.f,0.f,0.f,0.f}, (f32x4){0.f,0.f,0.f,0.f} };
    const hv8 vone = { (_Float16)1.f, (_Float16)1.f, (_Float16)1.f, (_Float16)1.f,
                       (_Float16)1.f, (_Float16)1.f, (_Float16)1.f, (_Float16)1.f };

    for (int kt = 0; kt < 16; ++kt) {
        // ---- issue next tile's global loads (consumed after the barrier)
        if (kt < 15) loadKV(kt + 1);

        // ---- per-row RH bias for this k-tile (broadcast reads)
        float rh[2][2][4];
        #pragma unroll
        for (int g = 0; g < 2; ++g)
            #pragma unroll
            for (int t2 = 0; t2 < 2; ++t2)
                #pragma unroll
                for (int r = 0; r < 4; ++r)
                    rh[g][t2][r] = (float)sH[wave*32 + g*16 + quad*4 + r][kt*2 + t2];

        // ---- scores + exp2 + pack P (swizzled, conflict-free writes)
        #pragma unroll
        for (int bb = 0; bb < 4; ++bb) {
            hv8 bK0 = *(const hv8*)&sK[bb*16 + l16][quad*8];
            hv8 bK1 = *(const hv8*)&sK[bb*16 + l16][32 + quad*8];
            #pragma unroll
            for (int g = 0; g < 2; ++g) {
                f32x4 c = {0.f,0.f,0.f,0.f};
                c = __builtin_amdgcn_mfma_f32_16x16x32_f16(aQ0[g], bK0, c, 0, 0, 0);
                c = __builtin_amdgcn_mfma_f32_16x16x32_f16(aQ1[g], bK1, c, 0, 0, 0);
                #pragma unroll
                for (int r = 0; r < 4; ++r) {
                    float p = fast_exp2(c[r] + rh[g][bb>>1][r] + rwReg[g][bb&1][r]);
                    sP[wave*PW2 + (g*16 + quad*4 + r)*72 + ((bb ^ quad) << 4) + l16] =
                        (_Float16)p;
                }
            }
        }

        // ---- reload P as A-fragments (inverse swizzle; row-pure key l16>>2)
        hv8 aP0[2], aP1[2];
        #pragma unroll
        for (int g = 0; g < 2; ++g) {
            const int base = wave*PW2 + (g*16 + l16)*72 + (quad & 1)*8;
            const int sw = l16 >> 2;
            aP0[g] = *(const hv8*)&sP[base + ((( (quad>>1)     ) ^ sw) << 4)];
            aP1[g] = *(const hv8*)&sP[base + ((( (quad>>1) | 2 ) ^ sw) << 4)];
        }

        __builtin_amdgcn_s_setprio(1);
        // ---- row-sum via MFMA with ones-B (replaces shfl_xor reduce)
        #pragma unroll
        for (int g = 0; g < 2; ++g) {
            lacc[g] = __builtin_amdgcn_mfma_f32_16x16x32_f16(aP0[g], vone, lacc[g], 0, 0, 0);
            lacc[g] = __builtin_amdgcn_mfma_f32_16x16x32_f16(aP1[g], vone, lacc[g], 0, 0, 0);
        }
        // ---- O += P @ V  (bV frags shared across both groups)
        #pragma unroll
        for (int n = 0; n < 4; ++n) {
            hv8 bV0 = *(const hv8*)&sVt[n*16 + l16][quad*8];
            hv8 bV1 = *(const hv8*)&sVt[n*16 + l16][32 + quad*8];
            #pragma unroll
            for (int g = 0; g < 2; ++g) {
                o[g][n] = __builtin_amdgcn_mfma_f32_16x16x32_f16(aP0[g], bV0, o[g][n], 0, 0, 0);
                o[g][n] = __builtin_amdgcn_mfma_f32_16x16x32_f16(aP1[g], bV1, o[g][n], 0, 0, 0);
            }
        }
        __builtin_amdgcn_s_setprio(0);

        __syncthreads();               // all waves done reading tile kt
        if (kt < 15) writeKV();        // vmcnt wait happened under compute
        __syncthreads();               // tile kt+1 visible
    }

    // ---- finalize: /l, fp16 out into [b, t, C]
    #pragma unroll
    for (int g = 0; g < 2; ++g) {
        float inv[4];
        #pragma unroll
        for (int r = 0; r < 4; ++r) inv[r] = 1.f / lacc[g][r];
        #pragma unroll
        for (int n = 0; n < 4; ++n)
            #pragma unroll
            for (int r = 0; r < 4; ++r) {
                int t = qt*128 + wave*32 + g*16 + quad*4 + r;
                size_t addr = ((size_t)b * TT + t) * CC + h*HD + n*16 + l16;
                O[addr] = (_Float16)(o[g][n][r] * inv[r]);
            }
    }
}

// ---------------------------------------------------------------------------
extern "C" void kernel_launch(void* const* d_in, const int* in_sizes, int n_in,
                              void* d_out, int out_size, void* d_ws, size_t ws_size,
                              hipStream_t stream) {
    const float* x   = (const float*)d_in[0];
    const float* ctx = (const float*)d_in[1];
    const float* Wq  = (const float*)d_in[2];
    const float* Wk  = (const float*)d_in[3];
    const float* Wv  = (const float*)d_in[4];
    const float* Wo  = (const float*)d_in[5];
    const float* bo  = (const float*)d_in[6];
    const float* rh  = (const float*)d_in[7];
    const float* rw  = (const float*)d_in[8];
    float* out = (float*)d_out;

    const size_t MN = (size_t)BB * TT * CC;   // 6291456
    const size_t WN = (size_t)CC * CC;        // 589824
    _Float16* p = (_Float16*)d_ws;
    _Float16* WqT = p; p += WN;
    _Float16* WkT = p; p += WN;
    _Float16* WvT = p; p += WN;
    _Float16* WoT = p; p += WN;
    _Float16* Qh  = p; p += MN;
    _Float16* Kh  = p; p += MN;
    _Float16* VtB = p; p += MN;
    _Float16* Oh  = p; p += MN;

    dim3 blk(256);

    transpose_w4<<<dim3(12, 12, 4), blk, 0, stream>>>(
        Wq, Wk, Wv, Wo, WqT, WkT, WvT, WoT);

    gemm_qkv3<<<dim3(CC/128, (BB*TT)/128, 3), blk, 0, stream>>>(
        x, ctx, WqT, WkT, WvT, Qh, Kh, VtB);

    attn_mfma<<<dim3(BB*NH*(TT/128)), blk, 0, stream>>>(
        Qh, Kh, VtB, rh, rw, Oh);

    gemm_out_f16<<<dim3(CC/64, (BB*TT)/128), blk, 0, stream>>>(
        Oh, WoT, bo, out);
}

// Round 4
// 235.969 us; speedup vs baseline: 1.1172x; 1.1172x over previous
//
#include <hip/hip_runtime.h>
#include <math.h>

#define BB 8
#define TT 1024
#define CC 768
#define NH 12
#define HD 64
#define LOG2E 1.44269504088896f

typedef __attribute__((ext_vector_type(8))) _Float16 hv8;   // 8 fp16 (4 VGPRs)
typedef __attribute__((ext_vector_type(8))) short  short8;  // raw 16B
typedef __attribute__((ext_vector_type(4))) float  f32x4;

static __device__ __forceinline__ float fast_exp2(float x) {
#if __has_builtin(__builtin_amdgcn_exp2f)
    return __builtin_amdgcn_exp2f(x);
#else
    return exp2f(x);
#endif
}

// Async global->LDS DMA, 16B per lane (global_load_lds_dwordx4).
// LDS dest must be wave-uniform base; HW writes base + lane*16.
static __device__ __forceinline__ void gload_lds16(
    const _Float16* __restrict__ g, _Float16* l)
{
    __builtin_amdgcn_global_load_lds(
        (const __attribute__((address_space(1))) void*)g,
        (__attribute__((address_space(3))) void*)l, 16, 0, 0);
}

// ---------------------------------------------------------------------------
// fp32 -> fp16 convert; grid.z selects x / ctx.  (Restored from R1: feeding
// the GEMM with fp16 A enables global_load_lds staging; R2/R3's f32-direct
// A cost +20us in qkv3 -- more than this kernel's ~11us.)
// ---------------------------------------------------------------------------
__global__ __launch_bounds__(256) void convert_f16x2(
    const float* __restrict__ x, const float* __restrict__ ctx,
    _Float16* __restrict__ xh, _Float16* __restrict__ ch, int n)
{
    const float* in = blockIdx.z ? ctx : x;
    _Float16* out   = blockIdx.z ? ch  : xh;
    int i = (blockIdx.x * 256 + threadIdx.x) * 8;
    if (i < n) {
        float4 v0 = *(const float4*)(in + i);
        float4 v1 = *(const float4*)(in + i + 4);
        hv8 h = { (_Float16)v0.x, (_Float16)v0.y, (_Float16)v0.z, (_Float16)v0.w,
                  (_Float16)v1.x, (_Float16)v1.y, (_Float16)v1.z, (_Float16)v1.w };
        *(hv8*)(out + i) = h;
    }
}

// ---------------------------------------------------------------------------
// All 4 weight transposes in one launch: WT[n][k] = W[k][n] * scale (fp16).
// Score scale 0.125 AND log2(e) folded into Wk (exp2 domain for attn).
// ---------------------------------------------------------------------------
__global__ __launch_bounds__(256) void transpose_w4(
    const float* __restrict__ Wq, const float* __restrict__ Wk,
    const float* __restrict__ Wv, const float* __restrict__ Wo,
    _Float16* __restrict__ WqT, _Float16* __restrict__ WkT,
    _Float16* __restrict__ WvT, _Float16* __restrict__ WoT)
{
    const int z = blockIdx.z;
    const float* W = (z == 0) ? Wq : (z == 1) ? Wk : (z == 2) ? Wv : Wo;
    _Float16*   WT = (z == 0) ? WqT : (z == 1) ? WkT : (z == 2) ? WvT : WoT;
    const float scale = (z == 1) ? 0.125f * LOG2E : 1.0f;

    __shared__ float tile[64][65];
    const int tx = threadIdx.x & 15, ty = threadIdx.x >> 4;
    const int n0 = blockIdx.x * 64, k0 = blockIdx.y * 64;

    #pragma unroll
    for (int ii = 0; ii < 4; ++ii) {
        int k = ty + ii * 16;
        float4 v = *(const float4*)(W + (size_t)(k0 + k) * CC + n0 + tx * 4);
        tile[k][tx*4+0] = v.x; tile[k][tx*4+1] = v.y;
        tile[k][tx*4+2] = v.z; tile[k][tx*4+3] = v.w;
    }
    __syncthreads();
    #pragma unroll
    for (int ii = 0; ii < 4; ++ii) {
        int n = ty + ii * 16;
        _Float16* dst = WT + (size_t)(n0 + n) * CC + k0 + tx * 4;
        dst[0] = (_Float16)(tile[tx*4+0][n] * scale);
        dst[1] = (_Float16)(tile[tx*4+1][n] * scale);
        dst[2] = (_Float16)(tile[tx*4+2][n] * scale);
        dst[3] = (_Float16)(tile[tx*4+3][n] * scale);
    }
}

// ---------------------------------------------------------------------------
// Fused QKV GEMM, one launch.  R4: m97-structure staging --
// global_load_lds_dwordx4 DMA into LINEAR unpadded [128][64] LDS tiles
// (no VGPR round-trip, no staging VALU), 2-barrier K-loop.  ds_read bank
// conflicts from the 128B row stride are off the critical path at this
// structure (stage+vmcnt+barrier dominates).  T1 bijective XCD swizzle on
// the flattened grid (1152 = 8 XCDs x 144): the 6 n-blocks sharing an
// A-panel land on one XCD's L2.
// z<2: LDS-bounce vectorized epilogue into [b,h,t,d].
// z==2 (V): stride-137 transpose bounce, t-contiguous stores into [b,h,d,t].
// ---------------------------------------------------------------------------
__global__ __launch_bounds__(256) void gemm_qkv3(
    const _Float16* __restrict__ xh, const _Float16* __restrict__ ch,
    const _Float16* __restrict__ WqT, const _Float16* __restrict__ WkT,
    const _Float16* __restrict__ WvT,
    _Float16* __restrict__ Qh, _Float16* __restrict__ Kh,
    _Float16* __restrict__ Vt)
{
    // T1: XCD k owns logical ids [k*144, (k+1)*144): consecutive logical ids
    // (x fastest) keep all 6 column-blocks of one A-panel on one XCD.
    const int bid = blockIdx.x;
    const int lid = (bid & 7) * 144 + (bid >> 3);
    const int z   = lid / 384;
    const int rem = lid - z * 384;
    const int by  = rem / 6;
    const int bx  = rem - by * 6;

    const _Float16* A  = (z == 0) ? xh : ch;
    const _Float16* BT = (z == 0) ? WqT : (z == 1) ? WkT : WvT;

    __shared__ _Float16 smem[128 * 137];   // loop: sA|sB (8K halves each); epi: sT
    _Float16* sA = smem;                   // [128][64] linear
    _Float16* sB = smem + 128 * 64;        // [128][64] linear

    const int tid  = threadIdx.x;
    const int wave = tid >> 6, lane = tid & 63;
    const int quad = lane >> 4, l16 = lane & 15;
    const int m0 = by * 128, n0 = bx * 128;
    const int mw = (wave & 1) * 64, nw = (wave >> 1) * 64;

    // each wave DMAs rows [wave*32, wave*32+32) of both tiles; lane covers
    // row sub = lane>>3, 16B chunk = lane&7 (matches HW's base+lane*16).
    const int srow = wave * 32 + (lane >> 3);
    const int scol = (lane & 7) * 8;

    f32x4 acc[4][4];
    #pragma unroll
    for (int i = 0; i < 4; ++i)
        #pragma unroll
        for (int j = 0; j < 4; ++j) acc[i][j] = (f32x4){0.f,0.f,0.f,0.f};

    for (int kt = 0; kt < CC; kt += 64) {
        #pragma unroll
        for (int i = 0; i < 4; ++i) {
            gload_lds16(A  + (size_t)(m0 + srow + i*8) * CC + kt + scol,
                        &sA[(wave*32 + i*8) * 64]);
            gload_lds16(BT + (size_t)(n0 + srow + i*8) * CC + kt + scol,
                        &sB[(wave*32 + i*8) * 64]);
        }
        __syncthreads();                 // drains vmcnt (DMA) + lgkm
        #pragma unroll
        for (int kk = 0; kk < 2; ++kk) {
            hv8 af[4], bf[4];
            #pragma unroll
            for (int mi = 0; mi < 4; ++mi)
                af[mi] = *(const hv8*)&sA[(mw + mi*16 + l16)*64 + kk*32 + quad*8];
            #pragma unroll
            for (int nj = 0; nj < 4; ++nj)
                bf[nj] = *(const hv8*)&sB[(nw + nj*16 + l16)*64 + kk*32 + quad*8];
            #pragma unroll
            for (int mi = 0; mi < 4; ++mi)
                #pragma unroll
                for (int nj = 0; nj < 4; ++nj)
                    acc[mi][nj] = __builtin_amdgcn_mfma_f32_16x16x32_f16(
                        af[mi], bf[nj], acc[mi][nj], 0, 0, 0);
        }
        __syncthreads();
    }

    if (z < 2) {
        // row-major bounce -> hv8 stores (128B segments) into [b,h,t,d]
        _Float16* Chead = (z == 0) ? Qh : Kh;
        _Float16* sT = smem;   // [128][137]
        #pragma unroll
        for (int mi = 0; mi < 4; ++mi)
            #pragma unroll
            for (int nj = 0; nj < 4; ++nj)
                #pragma unroll
                for (int r = 0; r < 4; ++r)
                    sT[(mw + mi*16 + quad*4 + r)*137 + nw + nj*16 + l16] =
                        (_Float16)acc[mi][nj][r];
        __syncthreads();
        #pragma unroll
        for (int ii = 0; ii < 8; ++ii) {
            int u = tid + ii * 256;
            int row = u >> 4;           // 0..127
            int chk = u & 15;           // 16 chunks of 8 halves
            hv8 o;
            #pragma unroll
            for (int j = 0; j < 8; ++j) o[j] = sT[row*137 + chk*8 + j];
            int gm = m0 + row, gn = n0 + chk*8;
            int bI = gm >> 10, tI = gm & 1023;
            int hI = gn >> 6,  dI = gn & 63;
            *(hv8*)(Chead + (((size_t)bI * NH + hI) * TT + tI) * HD + dI) = o;
        }
    } else {
        // V: stride-137 transpose bounce, then t-contiguous stores.
        _Float16* sT = smem;   // [128][137] = 17536 halves
        #pragma unroll
        for (int mi = 0; mi < 4; ++mi)
            #pragma unroll
            for (int nj = 0; nj < 4; ++nj)
                #pragma unroll
                for (int r = 0; r < 4; ++r)
                    sT[(mw + mi*16 + quad*4 + r)*137 + nw + nj*16 + l16] =
                        (_Float16)acc[mi][nj][r];
        __syncthreads();
        #pragma unroll
        for (int ii = 0; ii < 8; ++ii) {
            int u = tid + ii * 256;
            int dloc = u >> 4;          // 0..127
            int tch  = u & 15;          // consecutive lanes -> consecutive t
            hv8 o;
            #pragma unroll
            for (int j = 0; j < 8; ++j) o[j] = sT[(tch*8 + j)*137 + dloc];
            int gn = n0 + dloc;
            int hI = gn >> 6, dI = gn & 63;
            int gm = m0 + tch * 8;
            int bI = gm >> 10, tI = gm & 1023;
            *(hv8*)(Vt + (((size_t)bI * NH + hI) * HD + dI) * TT + tI) = o;
        }
    }
}

// ---------------------------------------------------------------------------
// fp16 single-pass output GEMM: out(fp32) = A @ BT^T + bias
// Tile 128x64, grid (12,64) = 768 blocks = 3/CU.
// R4: global_load_lds staging into linear [.][64] LDS (same as qkv3).
// ---------------------------------------------------------------------------
__global__ __launch_bounds__(256) void gemm_out_f16(
    const _Float16* __restrict__ A, const _Float16* __restrict__ BT,
    const float* __restrict__ bias, float* __restrict__ out)
{
    __shared__ _Float16 sA[128 * 64];
    __shared__ _Float16 sB[64 * 64];

    const int tid  = threadIdx.x;
    const int wave = tid >> 6, lane = tid & 63;
    const int quad = lane >> 4, l16 = lane & 15;
    const int m0 = blockIdx.y * 128, n0 = blockIdx.x * 64;
    const int mw = (wave & 1) * 64, nw = (wave >> 1) * 32;

    const int srow = lane >> 3;            // row sub within an 8-row DMA span
    const int scol = (lane & 7) * 8;

    f32x4 acc[4][2];
    #pragma unroll
    for (int i = 0; i < 4; ++i)
        #pragma unroll
        for (int j = 0; j < 2; ++j) acc[i][j] = (f32x4){0.f,0.f,0.f,0.f};

    for (int kt = 0; kt < CC; kt += 64) {
        #pragma unroll
        for (int i = 0; i < 4; ++i)
            gload_lds16(A + (size_t)(m0 + wave*32 + i*8 + srow) * CC + kt + scol,
                        &sA[(wave*32 + i*8) * 64]);
        #pragma unroll
        for (int i = 0; i < 2; ++i)
            gload_lds16(BT + (size_t)(n0 + wave*16 + i*8 + srow) * CC + kt + scol,
                        &sB[(wave*16 + i*8) * 64]);
        __syncthreads();
        #pragma unroll
        for (int kk = 0; kk < 2; ++kk) {
            hv8 af[4], bf[2];
            #pragma unroll
            for (int mi = 0; mi < 4; ++mi)
                af[mi] = *(const hv8*)&sA[(mw + mi*16 + l16)*64 + kk*32 + quad*8];
            #pragma unroll
            for (int nj = 0; nj < 2; ++nj)
                bf[nj] = *(const hv8*)&sB[(nw + nj*16 + l16)*64 + kk*32 + quad*8];
            #pragma unroll
            for (int mi = 0; mi < 4; ++mi)
                #pragma unroll
                for (int nj = 0; nj < 2; ++nj)
                    acc[mi][nj] = __builtin_amdgcn_mfma_f32_16x16x32_f16(
                        af[mi], bf[nj], acc[mi][nj], 0, 0, 0);
        }
        __syncthreads();
    }

    #pragma unroll
    for (int mi = 0; mi < 4; ++mi)
        #pragma unroll
        for (int nj = 0; nj < 2; ++nj)
            #pragma unroll
            for (int r = 0; r < 4; ++r) {
                int gm = m0 + mw + mi*16 + quad*4 + r;
                int gn = n0 + nw + nj*16 + l16;
                out[(size_t)gm * CC + gn] = acc[mi][nj][r] + bias[gn];
            }
}

// ---------------------------------------------------------------------------
// fp16 MFMA flash attention, BQ=128: 4 waves, each owns 32 q-rows.
// (byte-identical to R1's verified 66.4us version -- MFMA rowsum, exp2
// domain, sP XOR swizzle, T14 async staging, setprio around PV.)
// ---------------------------------------------------------------------------
#define PW2 (32*72 + 8)   // per-wave sP region stride (halves)

__global__ __launch_bounds__(256) void attn_mfma(
    const _Float16* __restrict__ Q, const _Float16* __restrict__ K,
    const _Float16* __restrict__ Vt, const float* __restrict__ relh,
    const float* __restrict__ relw, _Float16* __restrict__ O)
{
    __shared__ _Float16 sK [64][72];   // loop: K tile | prologue: relh window (35 rows)
    __shared__ _Float16 sVt[64][72];   // loop: Vt tile | prologue: relw rows
    __shared__ _Float16 sP [4*PW2];    // loop: per-wave P (32x64, XOR-swizzled) | prologue: Q + G
    __shared__ _Float16 sH [128][34];  // rh table [qi][hk]

    const int tid  = threadIdx.x;
    const int wave = tid >> 6, lane = tid & 63;
    const int quad = lane >> 4, l16 = lane & 15;

    const int bid = blockIdx.x;
    const int qt  = bid & 7;           // 128-row q tile, 8 per head
    const int bh  = bid >> 3;
    const int h   = bh % NH;
    const int b   = bh / NH;
    const size_t hbase = ((size_t)b * NH + h) * TT * HD;

    // ---- K/V tile prefetch registers (async staging)
    short8 pK[2], pV[2];
    auto loadKV = [&](int kt) {
        #pragma unroll
        for (int ii = 0; ii < 2; ++ii) {
            int u = tid + ii * 256;
            int row = u >> 3, c8 = u & 7;
            pK[ii] = *(const short8*)(K  + hbase + (size_t)(kt*64 + row) * HD + c8*8);
            pV[ii] = *(const short8*)(Vt + hbase + (size_t)row * TT + kt*64 + c8*8);
        }
    };
    auto writeKV = [&]() {
        #pragma unroll
        for (int ii = 0; ii < 2; ++ii) {
            int u = tid + ii * 256;
            int row = u >> 3, c8 = u & 7;
            *(short8*)&sK [row][c8*8] = pK[ii];
            *(short8*)&sVt[row][c8*8] = pV[ii];
        }
    };

    // ---- prologue staging: Q (stride-72 overlay on sP), relh window, relw
    //      relh/relw pre-scaled by log2e (exp2 domain).
    #pragma unroll
    for (int ii = 0; ii < 4; ++ii) {
        int u = tid + ii * 256;        // 0..1023
        int row = u >> 3, c8 = u & 7;
        *(short8*)&sP[row*72 + c8*8] =
            *(const short8*)(Q + hbase + (size_t)(qt*128 + row) * HD + c8*8);
    }
    #pragma unroll
    for (int ii = 0; ii < 2; ++ii) {
        int u = tid + ii * 256;
        if (u < 280) {                 // 35 rows x 8 chunks of relh window
            int row = u >> 3, c8 = u & 7;
            const float* src = relh + (size_t)(4*qt + row) * HD + c8*8;
            float4 v0 = *(const float4*)(src);
            float4 v1 = *(const float4*)(src + 4);
            hv8 s = { (_Float16)(v0.x*LOG2E), (_Float16)(v0.y*LOG2E),
                      (_Float16)(v0.z*LOG2E), (_Float16)(v0.w*LOG2E),
                      (_Float16)(v1.x*LOG2E), (_Float16)(v1.y*LOG2E),
                      (_Float16)(v1.z*LOG2E), (_Float16)(v1.w*LOG2E) };
            *(hv8*)&sK[row][c8*8] = s;
        }
    }
    #pragma unroll
    for (int ii = 0; ii < 2; ++ii) {
        int u = tid + ii * 256;
        int row = u >> 3, c8 = u & 7;
        int sr = row < 63 ? row : 62;
        const float* src = relw + (size_t)sr * HD + c8*8;
        float4 v0 = *(const float4*)(src);
        float4 v1 = *(const float4*)(src + 4);
        hv8 s = { (_Float16)(v0.x*LOG2E), (_Float16)(v0.y*LOG2E),
                  (_Float16)(v0.z*LOG2E), (_Float16)(v0.w*LOG2E),
                  (_Float16)(v1.x*LOG2E), (_Float16)(v1.y*LOG2E),
                  (_Float16)(v1.z*LOG2E), (_Float16)(v1.w*LOG2E) };
        *(hv8*)&sVt[row][c8*8] = s;
    }
    loadKV(0);                         // k-tile 0 in flight during prologue math
    __syncthreads();

    // ---- persistent Q A-fragments (2 groups of 16 rows per wave)
    hv8 aQ0[2], aQ1[2];
    #pragma unroll
    for (int g = 0; g < 2; ++g) {
        int qrow = wave*32 + g*16 + l16;
        aQ0[g] = *(const hv8*)&sP[qrow*72 + quad*8];
        aQ1[g] = *(const hv8*)&sP[qrow*72 + 32 + quad*8];
    }
    __syncthreads();   // all aQ loaded before G-writes clobber the overlay

    // ---- RH via MFMA: sH[qi][hk] = q . relh[hq-hk+31]; hq = qt*4+wave
    #pragma unroll
    for (int g = 0; g < 2; ++g)
        #pragma unroll
        for (int t = 0; t < 2; ++t) {
            int wr = wave + 31 - (t*16 + l16);       // window row, in [wave, wave+31]
            hv8 b0 = *(const hv8*)&sK[wr][quad*8];
            hv8 b1 = *(const hv8*)&sK[wr][32 + quad*8];
            f32x4 c = {0.f,0.f,0.f,0.f};
            c = __builtin_amdgcn_mfma_f32_16x16x32_f16(aQ0[g], b0, c, 0, 0, 0);
            c = __builtin_amdgcn_mfma_f32_16x16x32_f16(aQ1[g], b1, c, 0, 0, 0);
            #pragma unroll
            for (int r = 0; r < 4; ++r)
                sH[wave*32 + g*16 + quad*4 + r][t*16 + l16] = (_Float16)c[r];
        }
    // ---- G = Q @ relw^T into own-wave sP region (XOR-swizzled col blocks)
    #pragma unroll
    for (int g = 0; g < 2; ++g)
        #pragma unroll
        for (int t = 0; t < 4; ++t) {
            hv8 b0 = *(const hv8*)&sVt[t*16 + l16][quad*8];
            hv8 b1 = *(const hv8*)&sVt[t*16 + l16][32 + quad*8];
            f32x4 c = {0.f,0.f,0.f,0.f};
            c = __builtin_amdgcn_mfma_f32_16x16x32_f16(aQ0[g], b0, c, 0, 0, 0);
            c = __builtin_amdgcn_mfma_f32_16x16x32_f16(aQ1[g], b1, c, 0, 0, 0);
            #pragma unroll
            for (int r = 0; r < 4; ++r)
                sP[wave*PW2 + (g*16 + quad*4 + r)*72 + ((t ^ quad) << 4) + l16] =
                    (_Float16)c[r];
        }
    // ---- gather RW bias (own wave region; lgkmcnt orders same-wave LDS)
    float rwReg[2][2][4];
    #pragma unroll
    for (int g = 0; g < 2; ++g)
        #pragma unroll
        for (int j = 0; j < 2; ++j)
            #pragma unroll
            for (int r = 0; r < 4; ++r) {
                int idx = g*16 + quad*4 + r - j*16 - l16 + 31;   // 0..62 logical col
                int pc  = (((idx >> 4) ^ quad) << 4) | (idx & 15);
                rwReg[g][j][r] = (float)sP[wave*PW2 + (g*16 + quad*4 + r)*72 + pc];
            }
    __syncthreads();   // RH/RW reads of sK/sVt complete
    writeKV();         // k-tile 0 -> LDS
    __syncthreads();

    f32x4 o[2][4];
    #pragma unroll
    for (int g = 0; g < 2; ++g)
        #pragma unroll
        for (int n = 0; n < 4; ++n) o[g][n] = (f32x4){0.f,0.f,0.f,0.f};
    f32x4 lacc[2] = { (f32x4){0.f,0.f,0.f,0.f}, (f32x4){0.f,0.f,0.f,0.f} };
    const hv8 vone = { (_Float16)1.f, (_Float16)1.f, (_Float16)1.f, (_Float16)1.f,
                       (_Float16)1.f, (_Float16)1.f, (_Float16)1.f, (_Float16)1.f };

    for (int kt = 0; kt < 16; ++kt) {
        // ---- issue next tile's global loads (consumed after the barrier)
        if (kt < 15) loadKV(kt + 1);

        // ---- per-row RH bias for this k-tile (broadcast reads)
        float rh[2][2][4];
        #pragma unroll
        for (int g = 0; g < 2; ++g)
            #pragma unroll
            for (int t2 = 0; t2 < 2; ++t2)
                #pragma unroll
                for (int r = 0; r < 4; ++r)
                    rh[g][t2][r] = (float)sH[wave*32 + g*16 + quad*4 + r][kt*2 + t2];

        // ---- scores + exp2 + pack P (swizzled, conflict-free writes)
        #pragma unroll
        for (int bb = 0; bb < 4; ++bb) {
            hv8 bK0 = *(const hv8*)&sK[bb*16 + l16][quad*8];
            hv8 bK1 = *(const hv8*)&sK[bb*16 + l16][32 + quad*8];
            #pragma unroll
            for (int g = 0; g < 2; ++g) {
                f32x4 c = {0.f,0.f,0.f,0.f};
                c = __builtin_amdgcn_mfma_f32_16x16x32_f16(aQ0[g], bK0, c, 0, 0, 0);
                c = __builtin_amdgcn_mfma_f32_16x16x32_f16(aQ1[g], bK1, c, 0, 0, 0);
                #pragma unroll
                for (int r = 0; r < 4; ++r) {
                    float p = fast_exp2(c[r] + rh[g][bb>>1][r] + rwReg[g][bb&1][r]);
                    sP[wave*PW2 + (g*16 + quad*4 + r)*72 + ((bb ^ quad) << 4) + l16] =
                        (_Float16)p;
                }
            }
        }

        // ---- reload P as A-fragments (inverse swizzle; row-pure key l16>>2)
        hv8 aP0[2], aP1[2];
        #pragma unroll
        for (int g = 0; g < 2; ++g) {
            const int base = wave*PW2 + (g*16 + l16)*72 + (quad & 1)*8;
            const int sw = l16 >> 2;
            aP0[g] = *(const hv8*)&sP[base + ((( (quad>>1)     ) ^ sw) << 4)];
            aP1[g] = *(const hv8*)&sP[base + ((( (quad>>1) | 2 ) ^ sw) << 4)];
        }

        __builtin_amdgcn_s_setprio(1);
        // ---- row-sum via MFMA with ones-B (replaces shfl_xor reduce)
        #pragma unroll
        for (int g = 0; g < 2; ++g) {
            lacc[g] = __builtin_amdgcn_mfma_f32_16x16x32_f16(aP0[g], vone, lacc[g], 0, 0, 0);
            lacc[g] = __builtin_amdgcn_mfma_f32_16x16x32_f16(aP1[g], vone, lacc[g], 0, 0, 0);
        }
        // ---- O += P @ V  (bV frags shared across both groups)
        #pragma unroll
        for (int n = 0; n < 4; ++n) {
            hv8 bV0 = *(const hv8*)&sVt[n*16 + l16][quad*8];
            hv8 bV1 = *(const hv8*)&sVt[n*16 + l16][32 + quad*8];
            #pragma unroll
            for (int g = 0; g < 2; ++g) {
                o[g][n] = __builtin_amdgcn_mfma_f32_16x16x32_f16(aP0[g], bV0, o[g][n], 0, 0, 0);
                o[g][n] = __builtin_amdgcn_mfma_f32_16x16x32_f16(aP1[g], bV1, o[g][n], 0, 0, 0);
            }
        }
        __builtin_amdgcn_s_setprio(0);

        __syncthreads();               // all waves done reading tile kt
        if (kt < 15) writeKV();        // vmcnt wait happened under compute
        __syncthreads();               // tile kt+1 visible
    }

    // ---- finalize: /l, fp16 out into [b, t, C]
    #pragma unroll
    for (int g = 0; g < 2; ++g) {
        float inv[4];
        #pragma unroll
        for (int r = 0; r < 4; ++r) inv[r] = 1.f / lacc[g][r];
        #pragma unroll
        for (int n = 0; n < 4; ++n)
            #pragma unroll
            for (int r = 0; r < 4; ++r) {
                int t = qt*128 + wave*32 + g*16 + quad*4 + r;
                size_t addr = ((size_t)b * TT + t) * CC + h*HD + n*16 + l16;
                O[addr] = (_Float16)(o[g][n][r] * inv[r]);
            }
    }
}

// ---------------------------------------------------------------------------
extern "C" void kernel_launch(void* const* d_in, const int* in_sizes, int n_in,
                              void* d_out, int out_size, void* d_ws, size_t ws_size,
                              hipStream_t stream) {
    const float* x   = (const float*)d_in[0];
    const float* ctx = (const float*)d_in[1];
    const float* Wq  = (const float*)d_in[2];
    const float* Wk  = (const float*)d_in[3];
    const float* Wv  = (const float*)d_in[4];
    const float* Wo  = (const float*)d_in[5];
    const float* bo  = (const float*)d_in[6];
    const float* rh  = (const float*)d_in[7];
    const float* rw  = (const float*)d_in[8];
    float* out = (float*)d_out;

    const size_t MN = (size_t)BB * TT * CC;   // 6291456
    const size_t WN = (size_t)CC * CC;        // 589824
    _Float16* p = (_Float16*)d_ws;
    _Float16* xh  = p; p += MN;
    _Float16* ch  = p; p += MN;
    _Float16* WqT = p; p += WN;
    _Float16* WkT = p; p += WN;
    _Float16* WvT = p; p += WN;
    _Float16* WoT = p; p += WN;
    _Float16* Qh  = p; p += MN;
    _Float16* Kh  = p; p += MN;
    _Float16* VtB = p; p += MN;
    _Float16* Oh  = p; p += MN;

    dim3 blk(256);

    convert_f16x2<<<dim3(MN/2048, 1, 2), blk, 0, stream>>>(x, ctx, xh, ch, (int)MN);

    transpose_w4<<<dim3(12, 12, 4), blk, 0, stream>>>(
        Wq, Wk, Wv, Wo, WqT, WkT, WvT, WoT);

    gemm_qkv3<<<dim3(1152), blk, 0, stream>>>(
        xh, ch, WqT, WkT, WvT, Qh, Kh, VtB);

    attn_mfma<<<dim3(BB*NH*(TT/128)), blk, 0, stream>>>(
        Qh, Kh, VtB, rh, rw, Oh);

    gemm_out_f16<<<dim3(CC/64, (BB*TT)/128), blk, 0, stream>>>(
        Oh, WoT, bo, out);
}

// Round 5
// 229.913 us; speedup vs baseline: 1.1466x; 1.0263x over previous
//
#include <hip/hip_runtime.h>
#include <math.h>

#define BB 8
#define TT 1024
#define CC 768
#define NH 12
#define HD 64
#define LOG2E 1.44269504088896f

typedef __attribute__((ext_vector_type(8))) _Float16 hv8;   // 8 fp16 (4 VGPRs)
typedef __attribute__((ext_vector_type(8))) short  short8;  // raw 16B
typedef __attribute__((ext_vector_type(4))) float  f32x4;

static __device__ __forceinline__ float fast_exp2(float x) {
#if __has_builtin(__builtin_amdgcn_exp2f)
    return __builtin_amdgcn_exp2f(x);
#else
    return exp2f(x);
#endif
}

// Async global->LDS DMA, 16B per lane (global_load_lds_dwordx4).
// LDS dest must be wave-uniform base; HW writes base + lane*16.
static __device__ __forceinline__ void gload_lds16(
    const _Float16* __restrict__ g, _Float16* l)
{
    __builtin_amdgcn_global_load_lds(
        (const __attribute__((address_space(1))) void*)g,
        (__attribute__((address_space(3))) void*)l, 16, 0, 0);
}

// ---------------------------------------------------------------------------
// R5: fused prep -- fp32->fp16 convert of x/ctx (blocks 0..6143) AND the 4
// weight transposes (blocks 6144..6719) in ONE launch (one fewer dispatch
// gap; independent block work).  Wk carries 0.125*log2e (exp2 domain).
// ---------------------------------------------------------------------------
__global__ __launch_bounds__(256) void prep_fused(
    const float* __restrict__ x, const float* __restrict__ ctx,
    _Float16* __restrict__ xh, _Float16* __restrict__ ch, int n,
    const float* __restrict__ Wq, const float* __restrict__ Wk,
    const float* __restrict__ Wv, const float* __restrict__ Wo,
    _Float16* __restrict__ WqT, _Float16* __restrict__ WkT,
    _Float16* __restrict__ WvT, _Float16* __restrict__ WoT)
{
    __shared__ float tile[64][65];
    const int bid = blockIdx.x;

    if (bid < 6144) {
        // ---- convert: 3072 blocks for x, 3072 for ctx
        const float* in = (bid >= 3072) ? ctx : x;
        _Float16* out   = (bid >= 3072) ? ch  : xh;
        int bb2 = (bid >= 3072) ? bid - 3072 : bid;
        int i = (bb2 * 256 + threadIdx.x) * 8;
        if (i < n) {
            float4 v0 = *(const float4*)(in + i);
            float4 v1 = *(const float4*)(in + i + 4);
            hv8 h = { (_Float16)v0.x, (_Float16)v0.y, (_Float16)v0.z, (_Float16)v0.w,
                      (_Float16)v1.x, (_Float16)v1.y, (_Float16)v1.z, (_Float16)v1.w };
            *(hv8*)(out + i) = h;
        }
        return;
    }

    // ---- transpose: WT[n][k] = W[k][n] * scale
    const int t  = bid - 6144;            // 0..575
    const int z  = t / 144;
    const int rm = t - z * 144;
    const int by = rm / 12, bx = rm - by * 12;

    const float* W = (z == 0) ? Wq : (z == 1) ? Wk : (z == 2) ? Wv : Wo;
    _Float16*   WT = (z == 0) ? WqT : (z == 1) ? WkT : (z == 2) ? WvT : WoT;
    const float scale = (z == 1) ? 0.125f * LOG2E : 1.0f;

    const int tx = threadIdx.x & 15, ty = threadIdx.x >> 4;
    const int n0 = bx * 64, k0 = by * 64;

    #pragma unroll
    for (int ii = 0; ii < 4; ++ii) {
        int k = ty + ii * 16;
        float4 v = *(const float4*)(W + (size_t)(k0 + k) * CC + n0 + tx * 4);
        tile[k][tx*4+0] = v.x; tile[k][tx*4+1] = v.y;
        tile[k][tx*4+2] = v.z; tile[k][tx*4+3] = v.w;
    }
    __syncthreads();
    #pragma unroll
    for (int ii = 0; ii < 4; ++ii) {
        int nn = ty + ii * 16;
        _Float16* dst = WT + (size_t)(n0 + nn) * CC + k0 + tx * 4;
        dst[0] = (_Float16)(tile[tx*4+0][nn] * scale);
        dst[1] = (_Float16)(tile[tx*4+1][nn] * scale);
        dst[2] = (_Float16)(tile[tx*4+2][nn] * scale);
        dst[3] = (_Float16)(tile[tx*4+3][nn] * scale);
    }
}

// ---------------------------------------------------------------------------
// Fused QKV GEMM, one launch.  m97-structure staging (global_load_lds_dwordx4
// into LINEAR [128][64] LDS, 2-barrier K-loop) + bijective XCD swizzle.
// z<2: LDS-bounce vectorized epilogue into [b,h,t,d].
// z==2 (V): stride-137 transpose bounce, t-contiguous stores into [b,h,d,t].
// ---------------------------------------------------------------------------
__global__ __launch_bounds__(256) void gemm_qkv3(
    const _Float16* __restrict__ xh, const _Float16* __restrict__ ch,
    const _Float16* __restrict__ WqT, const _Float16* __restrict__ WkT,
    const _Float16* __restrict__ WvT,
    _Float16* __restrict__ Qh, _Float16* __restrict__ Kh,
    _Float16* __restrict__ Vt)
{
    // T1: XCD k owns logical ids [k*144, (k+1)*144): consecutive logical ids
    // (x fastest) keep all 6 column-blocks of one A-panel on one XCD.
    const int bid = blockIdx.x;
    const int lid = (bid & 7) * 144 + (bid >> 3);
    const int z   = lid / 384;
    const int rem = lid - z * 384;
    const int by  = rem / 6;
    const int bx  = rem - by * 6;

    const _Float16* A  = (z == 0) ? xh : ch;
    const _Float16* BT = (z == 0) ? WqT : (z == 1) ? WkT : WvT;

    __shared__ _Float16 smem[128 * 137];   // loop: sA|sB (8K halves each); epi: sT
    _Float16* sA = smem;                   // [128][64] linear
    _Float16* sB = smem + 128 * 64;        // [128][64] linear

    const int tid  = threadIdx.x;
    const int wave = tid >> 6, lane = tid & 63;
    const int quad = lane >> 4, l16 = lane & 15;
    const int m0 = by * 128, n0 = bx * 128;
    const int mw = (wave & 1) * 64, nw = (wave >> 1) * 64;

    const int srow = wave * 32 + (lane >> 3);
    const int scol = (lane & 7) * 8;

    f32x4 acc[4][4];
    #pragma unroll
    for (int i = 0; i < 4; ++i)
        #pragma unroll
        for (int j = 0; j < 4; ++j) acc[i][j] = (f32x4){0.f,0.f,0.f,0.f};

    for (int kt = 0; kt < CC; kt += 64) {
        #pragma unroll
        for (int i = 0; i < 4; ++i) {
            gload_lds16(A  + (size_t)(m0 + srow + i*8) * CC + kt + scol,
                        &sA[(wave*32 + i*8) * 64]);
            gload_lds16(BT + (size_t)(n0 + srow + i*8) * CC + kt + scol,
                        &sB[(wave*32 + i*8) * 64]);
        }
        __syncthreads();                 // drains vmcnt (DMA) + lgkm
        #pragma unroll
        for (int kk = 0; kk < 2; ++kk) {
            hv8 af[4], bf[4];
            #pragma unroll
            for (int mi = 0; mi < 4; ++mi)
                af[mi] = *(const hv8*)&sA[(mw + mi*16 + l16)*64 + kk*32 + quad*8];
            #pragma unroll
            for (int nj = 0; nj < 4; ++nj)
                bf[nj] = *(const hv8*)&sB[(nw + nj*16 + l16)*64 + kk*32 + quad*8];
            #pragma unroll
            for (int mi = 0; mi < 4; ++mi)
                #pragma unroll
                for (int nj = 0; nj < 4; ++nj)
                    acc[mi][nj] = __builtin_amdgcn_mfma_f32_16x16x32_f16(
                        af[mi], bf[nj], acc[mi][nj], 0, 0, 0);
        }
        __syncthreads();
    }

    if (z < 2) {
        // row-major bounce -> hv8 stores (128B segments) into [b,h,t,d]
        _Float16* Chead = (z == 0) ? Qh : Kh;
        _Float16* sT = smem;   // [128][137]
        #pragma unroll
        for (int mi = 0; mi < 4; ++mi)
            #pragma unroll
            for (int nj = 0; nj < 4; ++nj)
                #pragma unroll
                for (int r = 0; r < 4; ++r)
                    sT[(mw + mi*16 + quad*4 + r)*137 + nw + nj*16 + l16] =
                        (_Float16)acc[mi][nj][r];
        __syncthreads();
        #pragma unroll
        for (int ii = 0; ii < 8; ++ii) {
            int u = tid + ii * 256;
            int row = u >> 4;           // 0..127
            int chk = u & 15;           // 16 chunks of 8 halves
            hv8 o;
            #pragma unroll
            for (int j = 0; j < 8; ++j) o[j] = sT[row*137 + chk*8 + j];
            int gm = m0 + row, gn = n0 + chk*8;
            int bI = gm >> 10, tI = gm & 1023;
            int hI = gn >> 6,  dI = gn & 63;
            *(hv8*)(Chead + (((size_t)bI * NH + hI) * TT + tI) * HD + dI) = o;
        }
    } else {
        // V: stride-137 transpose bounce, then t-contiguous stores.
        _Float16* sT = smem;   // [128][137] = 17536 halves
        #pragma unroll
        for (int mi = 0; mi < 4; ++mi)
            #pragma unroll
            for (int nj = 0; nj < 4; ++nj)
                #pragma unroll
                for (int r = 0; r < 4; ++r)
                    sT[(mw + mi*16 + quad*4 + r)*137 + nw + nj*16 + l16] =
                        (_Float16)acc[mi][nj][r];
        __syncthreads();
        #pragma unroll
        for (int ii = 0; ii < 8; ++ii) {
            int u = tid + ii * 256;
            int dloc = u >> 4;          // 0..127
            int tch  = u & 15;          // consecutive lanes -> consecutive t
            hv8 o;
            #pragma unroll
            for (int j = 0; j < 8; ++j) o[j] = sT[(tch*8 + j)*137 + dloc];
            int gn = n0 + dloc;
            int hI = gn >> 6, dI = gn & 63;
            int gm = m0 + tch * 8;
            int bI = gm >> 10, tI = gm & 1023;
            *(hv8*)(Vt + (((size_t)bI * NH + hI) * HD + dI) * TT + tI) = o;
        }
    }
}

// ---------------------------------------------------------------------------
// fp16 single-pass output GEMM: out(fp32) = A @ BT^T + bias
// Tile 128x64, 768 blocks = 3/CU.  R5: bijective XCD swizzle -- each 128-row
// A-panel (196KB) is consumed by 12 n-blocks; keep them on one XCD's L2.
// ---------------------------------------------------------------------------
__global__ __launch_bounds__(256) void gemm_out_f16(
    const _Float16* __restrict__ A, const _Float16* __restrict__ BT,
    const float* __restrict__ bias, float* __restrict__ out)
{
    __shared__ _Float16 sA[128 * 64];
    __shared__ _Float16 sB[64 * 64];

    const int bid = blockIdx.x;
    const int lid = (bid & 7) * 96 + (bid >> 3);   // 768 = 8 x 96, bijective
    const int by  = lid / 12;
    const int bx  = lid - by * 12;

    const int tid  = threadIdx.x;
    const int wave = tid >> 6, lane = tid & 63;
    const int quad = lane >> 4, l16 = lane & 15;
    const int m0 = by * 128, n0 = bx * 64;
    const int mw = (wave & 1) * 64, nw = (wave >> 1) * 32;

    const int srow = lane >> 3;            // row sub within an 8-row DMA span
    const int scol = (lane & 7) * 8;

    f32x4 acc[4][2];
    #pragma unroll
    for (int i = 0; i < 4; ++i)
        #pragma unroll
        for (int j = 0; j < 2; ++j) acc[i][j] = (f32x4){0.f,0.f,0.f,0.f};

    for (int kt = 0; kt < CC; kt += 64) {
        #pragma unroll
        for (int i = 0; i < 4; ++i)
            gload_lds16(A + (size_t)(m0 + wave*32 + i*8 + srow) * CC + kt + scol,
                        &sA[(wave*32 + i*8) * 64]);
        #pragma unroll
        for (int i = 0; i < 2; ++i)
            gload_lds16(BT + (size_t)(n0 + wave*16 + i*8 + srow) * CC + kt + scol,
                        &sB[(wave*16 + i*8) * 64]);
        __syncthreads();
        #pragma unroll
        for (int kk = 0; kk < 2; ++kk) {
            hv8 af[4], bf[2];
            #pragma unroll
            for (int mi = 0; mi < 4; ++mi)
                af[mi] = *(const hv8*)&sA[(mw + mi*16 + l16)*64 + kk*32 + quad*8];
            #pragma unroll
            for (int nj = 0; nj < 2; ++nj)
                bf[nj] = *(const hv8*)&sB[(nw + nj*16 + l16)*64 + kk*32 + quad*8];
            #pragma unroll
            for (int mi = 0; mi < 4; ++mi)
                #pragma unroll
                for (int nj = 0; nj < 2; ++nj)
                    acc[mi][nj] = __builtin_amdgcn_mfma_f32_16x16x32_f16(
                        af[mi], bf[nj], acc[mi][nj], 0, 0, 0);
        }
        __syncthreads();
    }

    #pragma unroll
    for (int mi = 0; mi < 4; ++mi)
        #pragma unroll
        for (int nj = 0; nj < 2; ++nj)
            #pragma unroll
            for (int r = 0; r < 4; ++r) {
                int gm = m0 + mw + mi*16 + quad*4 + r;
                int gn = n0 + nw + nj*16 + l16;
                out[(size_t)gm * CC + gn] = acc[mi][nj][r] + bias[gn];
            }
}

// ---------------------------------------------------------------------------
// fp16 MFMA flash attention, BQ=128: 4 waves, each owns 32 q-rows.
// R5: bijective XCD swizzle -- the 8 q-tile blocks sharing one (b,h)'s
// 256KB K/V land on the SAME XCD (bh = xcd + 8*(idx>>3)); 12 bh x 256KB =
// 3MB fits the 4MB per-XCD L2, all 96 blocks/XCD co-resident.  R4 counters
// showed FETCH=104.7MB vs ~38MB unique = 8x K/V re-fetch from HBM.
// (Loop body byte-identical to the verified R1 kernel.)
// ---------------------------------------------------------------------------
#define PW2 (32*72 + 8)   // per-wave sP region stride (halves)

__global__ __launch_bounds__(256) void attn_mfma(
    const _Float16* __restrict__ Q, const _Float16* __restrict__ K,
    const _Float16* __restrict__ Vt, const float* __restrict__ relh,
    const float* __restrict__ relw, _Float16* __restrict__ O)
{
    __shared__ _Float16 sK [64][72];   // loop: K tile | prologue: relh window (35 rows)
    __shared__ _Float16 sVt[64][72];   // loop: Vt tile | prologue: relw rows
    __shared__ _Float16 sP [4*PW2];    // loop: per-wave P (32x64, XOR-swizzled) | prologue: Q + G
    __shared__ _Float16 sH [128][34];  // rh table [qi][hk]

    const int tid  = threadIdx.x;
    const int wave = tid >> 6, lane = tid & 63;
    const int quad = lane >> 4, l16 = lane & 15;

    // T1 swizzle: XCD = bid&7 (round-robin dispatch), 96 blocks per XCD,
    // grouped as 12 bh x 8 qt so K/V reuse is XCD-local.
    const int bid = blockIdx.x;
    const int idx = bid >> 3;
    const int qt  = idx & 7;                    // 128-row q tile, 8 per head
    const int bh  = (bid & 7) + 8 * (idx >> 3); // bijective over 0..95
    const int h   = bh % NH;
    const int b   = bh / NH;
    const size_t hbase = ((size_t)b * NH + h) * TT * HD;

    // ---- K/V tile prefetch registers (async staging)
    short8 pK[2], pV[2];
    auto loadKV = [&](int kt) {
        #pragma unroll
        for (int ii = 0; ii < 2; ++ii) {
            int u = tid + ii * 256;
            int row = u >> 3, c8 = u & 7;
            pK[ii] = *(const short8*)(K  + hbase + (size_t)(kt*64 + row) * HD + c8*8);
            pV[ii] = *(const short8*)(Vt + hbase + (size_t)row * TT + kt*64 + c8*8);
        }
    };
    auto writeKV = [&]() {
        #pragma unroll
        for (int ii = 0; ii < 2; ++ii) {
            int u = tid + ii * 256;
            int row = u >> 3, c8 = u & 7;
            *(short8*)&sK [row][c8*8] = pK[ii];
            *(short8*)&sVt[row][c8*8] = pV[ii];
        }
    };

    // ---- prologue staging: Q (stride-72 overlay on sP), relh window, relw
    //      relh/relw pre-scaled by log2e (exp2 domain).
    #pragma unroll
    for (int ii = 0; ii < 4; ++ii) {
        int u = tid + ii * 256;        // 0..1023
        int row = u >> 3, c8 = u & 7;
        *(short8*)&sP[row*72 + c8*8] =
            *(const short8*)(Q + hbase + (size_t)(qt*128 + row) * HD + c8*8);
    }
    #pragma unroll
    for (int ii = 0; ii < 2; ++ii) {
        int u = tid + ii * 256;
        if (u < 280) {                 // 35 rows x 8 chunks of relh window
            int row = u >> 3, c8 = u & 7;
            const float* src = relh + (size_t)(4*qt + row) * HD + c8*8;
            float4 v0 = *(const float4*)(src);
            float4 v1 = *(const float4*)(src + 4);
            hv8 s = { (_Float16)(v0.x*LOG2E), (_Float16)(v0.y*LOG2E),
                      (_Float16)(v0.z*LOG2E), (_Float16)(v0.w*LOG2E),
                      (_Float16)(v1.x*LOG2E), (_Float16)(v1.y*LOG2E),
                      (_Float16)(v1.z*LOG2E), (_Float16)(v1.w*LOG2E) };
            *(hv8*)&sK[row][c8*8] = s;
        }
    }
    #pragma unroll
    for (int ii = 0; ii < 2; ++ii) {
        int u = tid + ii * 256;
        int row = u >> 3, c8 = u & 7;
        int sr = row < 63 ? row : 62;
        const float* src = relw + (size_t)sr * HD + c8*8;
        float4 v0 = *(const float4*)(src);
        float4 v1 = *(const float4*)(src + 4);
        hv8 s = { (_Float16)(v0.x*LOG2E), (_Float16)(v0.y*LOG2E),
                  (_Float16)(v0.z*LOG2E), (_Float16)(v0.w*LOG2E),
                  (_Float16)(v1.x*LOG2E), (_Float16)(v1.y*LOG2E),
                  (_Float16)(v1.z*LOG2E), (_Float16)(v1.w*LOG2E) };
        *(hv8*)&sVt[row][c8*8] = s;
    }
    loadKV(0);                         // k-tile 0 in flight during prologue math
    __syncthreads();

    // ---- persistent Q A-fragments (2 groups of 16 rows per wave)
    hv8 aQ0[2], aQ1[2];
    #pragma unroll
    for (int g = 0; g < 2; ++g) {
        int qrow = wave*32 + g*16 + l16;
        aQ0[g] = *(const hv8*)&sP[qrow*72 + quad*8];
        aQ1[g] = *(const hv8*)&sP[qrow*72 + 32 + quad*8];
    }
    __syncthreads();   // all aQ loaded before G-writes clobber the overlay

    // ---- RH via MFMA: sH[qi][hk] = q . relh[hq-hk+31]; hq = qt*4+wave
    #pragma unroll
    for (int g = 0; g < 2; ++g)
        #pragma unroll
        for (int t = 0; t < 2; ++t) {
            int wr = wave + 31 - (t*16 + l16);       // window row, in [wave, wave+31]
            hv8 b0 = *(const hv8*)&sK[wr][quad*8];
            hv8 b1 = *(const hv8*)&sK[wr][32 + quad*8];
            f32x4 c = {0.f,0.f,0.f,0.f};
            c = __builtin_amdgcn_mfma_f32_16x16x32_f16(aQ0[g], b0, c, 0, 0, 0);
            c = __builtin_amdgcn_mfma_f32_16x16x32_f16(aQ1[g], b1, c, 0, 0, 0);
            #pragma unroll
            for (int r = 0; r < 4; ++r)
                sH[wave*32 + g*16 + quad*4 + r][t*16 + l16] = (_Float16)c[r];
        }
    // ---- G = Q @ relw^T into own-wave sP region (XOR-swizzled col blocks)
    #pragma unroll
    for (int g = 0; g < 2; ++g)
        #pragma unroll
        for (int t = 0; t < 4; ++t) {
            hv8 b0 = *(const hv8*)&sVt[t*16 + l16][quad*8];
            hv8 b1 = *(const hv8*)&sVt[t*16 + l16][32 + quad*8];
            f32x4 c = {0.f,0.f,0.f,0.f};
            c = __builtin_amdgcn_mfma_f32_16x16x32_f16(aQ0[g], b0, c, 0, 0, 0);
            c = __builtin_amdgcn_mfma_f32_16x16x32_f16(aQ1[g], b1, c, 0, 0, 0);
            #pragma unroll
            for (int r = 0; r < 4; ++r)
                sP[wave*PW2 + (g*16 + quad*4 + r)*72 + ((t ^ quad) << 4) + l16] =
                    (_Float16)c[r];
        }
    // ---- gather RW bias (own wave region; lgkmcnt orders same-wave LDS)
    float rwReg[2][2][4];
    #pragma unroll
    for (int g = 0; g < 2; ++g)
        #pragma unroll
        for (int j = 0; j < 2; ++j)
            #pragma unroll
            for (int r = 0; r < 4; ++r) {
                int idx2 = g*16 + quad*4 + r - j*16 - l16 + 31;   // 0..62 logical col
                int pc  = (((idx2 >> 4) ^ quad) << 4) | (idx2 & 15);
                rwReg[g][j][r] = (float)sP[wave*PW2 + (g*16 + quad*4 + r)*72 + pc];
            }
    __syncthreads();   // RH/RW reads of sK/sVt complete
    writeKV();         // k-tile 0 -> LDS
    __syncthreads();

    f32x4 o[2][4];
    #pragma unroll
    for (int g = 0; g < 2; ++g)
        #pragma unroll
        for (int n = 0; n < 4; ++n) o[g][n] = (f32x4){0.f,0.f,0.f,0.f};
    f32x4 lacc[2] = { (f32x4){0.f,0.f,0.f,0.f}, (f32x4){0.f,0.f,0.f,0.f} };
    const hv8 vone = { (_Float16)1.f, (_Float16)1.f, (_Float16)1.f, (_Float16)1.f,
                       (_Float16)1.f, (_Float16)1.f, (_Float16)1.f, (_Float16)1.f };

    for (int kt = 0; kt < 16; ++kt) {
        // ---- issue next tile's global loads (consumed after the barrier)
        if (kt < 15) loadKV(kt + 1);

        // ---- per-row RH bias for this k-tile (broadcast reads)
        float rh[2][2][4];
        #pragma unroll
        for (int g = 0; g < 2; ++g)
            #pragma unroll
            for (int t2 = 0; t2 < 2; ++t2)
                #pragma unroll
                for (int r = 0; r < 4; ++r)
                    rh[g][t2][r] = (float)sH[wave*32 + g*16 + quad*4 + r][kt*2 + t2];

        // ---- scores + exp2 + pack P (swizzled, conflict-free writes)
        #pragma unroll
        for (int bb = 0; bb < 4; ++bb) {
            hv8 bK0 = *(const hv8*)&sK[bb*16 + l16][quad*8];
            hv8 bK1 = *(const hv8*)&sK[bb*16 + l16][32 + quad*8];
            #pragma unroll
            for (int g = 0; g < 2; ++g) {
                f32x4 c = {0.f,0.f,0.f,0.f};
                c = __builtin_amdgcn_mfma_f32_16x16x32_f16(aQ0[g], bK0, c, 0, 0, 0);
                c = __builtin_amdgcn_mfma_f32_16x16x32_f16(aQ1[g], bK1, c, 0, 0, 0);
                #pragma unroll
                for (int r = 0; r < 4; ++r) {
                    float p = fast_exp2(c[r] + rh[g][bb>>1][r] + rwReg[g][bb&1][r]);
                    sP[wave*PW2 + (g*16 + quad*4 + r)*72 + ((bb ^ quad) << 4) + l16] =
                        (_Float16)p;
                }
            }
        }

        // ---- reload P as A-fragments (inverse swizzle; row-pure key l16>>2)
        hv8 aP0[2], aP1[2];
        #pragma unroll
        for (int g = 0; g < 2; ++g) {
            const int base = wave*PW2 + (g*16 + l16)*72 + (quad & 1)*8;
            const int sw = l16 >> 2;
            aP0[g] = *(const hv8*)&sP[base + ((( (quad>>1)     ) ^ sw) << 4)];
            aP1[g] = *(const hv8*)&sP[base + ((( (quad>>1) | 2 ) ^ sw) << 4)];
        }

        __builtin_amdgcn_s_setprio(1);
        // ---- row-sum via MFMA with ones-B (replaces shfl_xor reduce)
        #pragma unroll
        for (int g = 0; g < 2; ++g) {
            lacc[g] = __builtin_amdgcn_mfma_f32_16x16x32_f16(aP0[g], vone, lacc[g], 0, 0, 0);
            lacc[g] = __builtin_amdgcn_mfma_f32_16x16x32_f16(aP1[g], vone, lacc[g], 0, 0, 0);
        }
        // ---- O += P @ V  (bV frags shared across both groups)
        #pragma unroll
        for (int n = 0; n < 4; ++n) {
            hv8 bV0 = *(const hv8*)&sVt[n*16 + l16][quad*8];
            hv8 bV1 = *(const hv8*)&sVt[n*16 + l16][32 + quad*8];
            #pragma unroll
            for (int g = 0; g < 2; ++g) {
                o[g][n] = __builtin_amdgcn_mfma_f32_16x16x32_f16(aP0[g], bV0, o[g][n], 0, 0, 0);
                o[g][n] = __builtin_amdgcn_mfma_f32_16x16x32_f16(aP1[g], bV1, o[g][n], 0, 0, 0);
            }
        }
        __builtin_amdgcn_s_setprio(0);

        __syncthreads();               // all waves done reading tile kt
        if (kt < 15) writeKV();        // vmcnt wait happened under compute
        __syncthreads();               // tile kt+1 visible
    }

    // ---- finalize: /l, fp16 out into [b, t, C]
    #pragma unroll
    for (int g = 0; g < 2; ++g) {
        float inv[4];
        #pragma unroll
        for (int r = 0; r < 4; ++r) inv[r] = 1.f / lacc[g][r];
        #pragma unroll
        for (int n = 0; n < 4; ++n)
            #pragma unroll
            for (int r = 0; r < 4; ++r) {
                int t = qt*128 + wave*32 + g*16 + quad*4 + r;
                size_t addr = ((size_t)b * TT + t) * CC + h*HD + n*16 + l16;
                O[addr] = (_Float16)(o[g][n][r] * inv[r]);
            }
    }
}

// ---------------------------------------------------------------------------
extern "C" void kernel_launch(void* const* d_in, const int* in_sizes, int n_in,
                              void* d_out, int out_size, void* d_ws, size_t ws_size,
                              hipStream_t stream) {
    const float* x   = (const float*)d_in[0];
    const float* ctx = (const float*)d_in[1];
    const float* Wq  = (const float*)d_in[2];
    const float* Wk  = (const float*)d_in[3];
    const float* Wv  = (const float*)d_in[4];
    const float* Wo  = (const float*)d_in[5];
    const float* bo  = (const float*)d_in[6];
    const float* rh  = (const float*)d_in[7];
    const float* rw  = (const float*)d_in[8];
    float* out = (float*)d_out;

    const size_t MN = (size_t)BB * TT * CC;   // 6291456
    const size_t WN = (size_t)CC * CC;        // 589824
    _Float16* p = (_Float16*)d_ws;
    _Float16* xh  = p; p += MN;
    _Float16* ch  = p; p += MN;
    _Float16* WqT = p; p += WN;
    _Float16* WkT = p; p += WN;
    _Float16* WvT = p; p += WN;
    _Float16* WoT = p; p += WN;
    _Float16* Qh  = p; p += MN;
    _Float16* Kh  = p; p += MN;
    _Float16* VtB = p; p += MN;
    _Float16* Oh  = p; p += MN;

    dim3 blk(256);

    prep_fused<<<dim3(6720), blk, 0, stream>>>(
        x, ctx, xh, ch, (int)MN, Wq, Wk, Wv, Wo, WqT, WkT, WvT, WoT);

    gemm_qkv3<<<dim3(1152), blk, 0, stream>>>(
        xh, ch, WqT, WkT, WvT, Qh, Kh, VtB);

    attn_mfma<<<dim3(BB*NH*(TT/128)), blk, 0, stream>>>(
        Qh, Kh, VtB, rh, rw, Oh);

    gemm_out_f16<<<dim3(768), blk, 0, stream>>>(
        Oh, WoT, bo, out);
}